// Round 12
// baseline (94.242 us; speedup 1.0000x reference)
//
#include <hip/hip_runtime.h>

typedef float f4 __attribute__((ext_vector_type(4)));

#define MLPB 16

// Monotone ticket counter for k_mlp's 16-block barriers. __device__ global:
// zero-init at module load, never reset; each barrier waits for the next
// multiple of MLPB, so it stays correct across arbitrary graph replays.
__device__ unsigned long long g_bar;

__device__ __forceinline__ void mlp_bar() {
    __syncthreads();
    if (threadIdx.x == 0) {
        __threadfence();
        unsigned long long t = __hip_atomic_fetch_add(&g_bar, 1ull, __ATOMIC_ACQ_REL,
                                                      __HIP_MEMORY_SCOPE_AGENT) + 1ull;
        unsigned long long target = ((t - 1ull) / MLPB + 1ull) * MLPB;
        while (__hip_atomic_load(&g_bar, __ATOMIC_ACQUIRE, __HIP_MEMORY_SCOPE_AGENT) < target)
            __builtin_amdgcn_s_sleep(1);
        __threadfence();
    }
    __syncthreads();
}

// Uniform row pointer into concatenated v_t_d / v_l_d:
// [vmain(384) | v1(64) | v2(32) | v0(64)] along tokens
__device__ __forceinline__ const float* vd_row(const float* vmain, const float* v0,
                                               const float* v1, const float* v2,
                                               int b, int t) {
    if (t < 384)      return vmain + ((size_t)b * 384 + t) * 128;
    else if (t < 448) return v1    + ((size_t)b * 64 + (t - 384)) * 128;
    else if (t < 480) return v2    + ((size_t)b * 32 + (t - 448)) * 128;
    else              return v0    + ((size_t)b * 64 + (t - 480)) * 128;
}

// Stage W[128][128] into LDS transposed: w_lds[k*129 + d] = W[d][k].
// Global reads coalesced f4; LDS writes 4-way aliased b32 (cheap, done once).
// Compute reads w_lds[k*129+d] with lane=d -> (k+d)%32 banks = 2-way = free.
__device__ __forceinline__ void stage_wt(const float* __restrict__ W, float* w_lds, int tid) {
    #pragma unroll 8
    for (int m = 0; m < 32; ++m) {
        int g = m * 128 + tid;          // f4 index 0..4095
        int dsrc = g >> 5;
        int k4 = (g & 31) * 4;
        f4 wv = ((const f4*)W)[g];
        w_lds[(k4 + 0) * 129 + dsrc] = wv[0];
        w_lds[(k4 + 1) * 129 + dsrc] = wv[1];
        w_lds[(k4 + 2) * 129 + dsrc] = wv[2];
        w_lds[(k4 + 3) * 129 + dsrc] = wv[3];
    }
}

// K1: att, 8 tokens/block, W self-staged transposed in LDS (no k_tr dispatch).
// attT[side][b][d][t] (t-contiguous for k_pair's coalesced staging).
// tc==0/side==0 blocks zero the x4 slabs.
__global__ __launch_bounds__(128) void k_att(const float* __restrict__ v0, const float* __restrict__ v1,
                                             const float* __restrict__ v2, const float* __restrict__ vt,
                                             const float* __restrict__ vl,
                                             const float* __restrict__ Wt, const float* __restrict__ bt,
                                             const float* __restrict__ Wl, const float* __restrict__ bl,
                                             float* __restrict__ attT, float* __restrict__ x4) {
    int tc = blockIdx.x, b = blockIdx.y, side = blockIdx.z;
    int d = threadIdx.x;
    __shared__ float w_lds[128 * 129];
    __shared__ float rows[8 * 128];
    if (tc == 0 && side == 0) {
        for (int i = d; i < 1024; i += 128)
            x4[(i >> 8) * 512 + b * 256 + (i & 255)] = 0.f;
    }
    const float* vmain = side ? vl : vt;
    stage_wt(side ? Wl : Wt, w_lds, d);
    #pragma unroll
    for (int i = 0; i < 8; ++i)
        rows[i * 128 + d] = vd_row(vmain, v0, v1, v2, b, tc * 8 + i)[d];
    __syncthreads();
    float bv = (side ? bl : bt)[d];
    float acc[8];
    #pragma unroll
    for (int i = 0; i < 8; ++i) acc[i] = bv;
    #pragma unroll 2
    for (int kc = 0; kc < 32; ++kc) {
        float w0 = w_lds[(kc * 4 + 0) * 129 + d];
        float w1 = w_lds[(kc * 4 + 1) * 129 + d];
        float w2 = w_lds[(kc * 4 + 2) * 129 + d];
        float w3 = w_lds[(kc * 4 + 3) * 129 + d];
        #pragma unroll
        for (int i = 0; i < 8; ++i) {
            f4 r = *(const f4*)&rows[i * 128 + kc * 4];   // LDS broadcast
            acc[i] += r[0] * w0 + r[1] * w1 + r[2] * w2 + r[3] * w3;
        }
    }
    size_t base = ((size_t)(side * 2 + b) * 128 + d) * 544 + tc * 8;
    #pragma unroll
    for (int i = 0; i < 8; ++i) attT[base + i] = acc[i];
}

// K2: S[so][b][t][d]; lrelu(x)=0.505x+0.495|x| => sum_l lrelu(c+o[l]) =
// 0.505*(544c+sum_o)+0.495*sum|c+o[l]|. Rows staged coalesced; inner loop LDS
// broadcast f4 -> 2-VALU/element floor. (Unchanged, proven.)
__global__ __launch_bounds__(256, 2) void k_pair(const float* __restrict__ attT,
                                                 float* __restrict__ S) {
    const int d = blockIdx.x, b = blockIdx.y, so = blockIdx.z;
    const int tid = threadIdx.x, lane = tid & 63, wvid = tid >> 6;
    __shared__ float rows[1088];
    __shared__ float red[4];
    const float* trow_g = attT + ((size_t)(0 * 2 + b) * 128 + d) * 544;
    const float* lrow_g = attT + ((size_t)(1 * 2 + b) * 128 + d) * 544;
    for (int i = tid; i < 544; i += 256) {
        rows[i]       = trow_g[i];
        rows[544 + i] = lrow_g[i];
    }
    __syncthreads();

    const float* selfr  = rows + so * 544;
    const float* otherr = rows + (1 - so) * 544;
    float p = 0.f;
    for (int i = tid; i < 544; i += 256) p += otherr[i];
    #pragma unroll
    for (int off = 32; off > 0; off >>= 1) p += __shfl_down(p, off, 64);
    if (lane == 0) red[wvid] = p;
    __syncthreads();
    const float sum_o = red[0] + red[1] + red[2] + red[3];

    const f4* or4 = (const f4*)otherr;
    for (int t = tid; t < 544; t += 256) {
        float c = selfr[t];
        float s0 = 0.f, s1 = 0.f, s2 = 0.f, s3 = 0.f;
        #pragma unroll 4
        for (int l4 = 0; l4 < 136; ++l4) {
            f4 o = or4[l4];
            s0 += fabsf(c + o[0]);
            s1 += fabsf(c + o[1]);
            s2 += fabsf(c + o[2]);
            s3 += fabsf(c + o[3]);
        }
        float s = (s0 + s1) + (s2 + s3);
        S[((size_t)(so * 2 + b) * 544 + t) * 128 + d] =
            (0.505f * (544.f * c + sum_o) + 0.495f * s) * (1.0f / 544.f);
    }
}

// K3: atte = sigmoid(S @ Wa^T + ba), 8 tokens/block, Wa self-staged transposed;
// gated 8-token partial -> ONE atomicAdd into slab tc&3 (chain depth 17).
__global__ __launch_bounds__(128) void k_atte(const float* __restrict__ S, const float* __restrict__ Wa,
                                              const float* __restrict__ ba,
                                              const float* __restrict__ v0, const float* __restrict__ v1,
                                              const float* __restrict__ v2, const float* __restrict__ vt,
                                              const float* __restrict__ vl,
                                              float* __restrict__ out, float* __restrict__ x4) {
    int tc = blockIdx.x, b = blockIdx.y, side = blockIdx.z;
    int d = threadIdx.x;
    __shared__ float w_lds[128 * 129];
    __shared__ float srows[8 * 128];
    stage_wt(Wa, w_lds, d);
    const float* sbase = S + ((size_t)(side * 2 + b) * 544 + tc * 8) * 128;
    #pragma unroll
    for (int i = 0; i < 8; ++i) srows[i * 128 + d] = sbase[i * 128 + d];
    __syncthreads();
    float bv = ba[d];
    float acc[8];
    #pragma unroll
    for (int i = 0; i < 8; ++i) acc[i] = bv;
    #pragma unroll 2
    for (int kc = 0; kc < 32; ++kc) {
        float w0 = w_lds[(kc * 4 + 0) * 129 + d];
        float w1 = w_lds[(kc * 4 + 1) * 129 + d];
        float w2 = w_lds[(kc * 4 + 2) * 129 + d];
        float w3 = w_lds[(kc * 4 + 3) * 129 + d];
        #pragma unroll
        for (int i = 0; i < 8; ++i) {
            f4 r = *(const f4*)&srows[i * 128 + kc * 4];
            acc[i] += r[0] * w0 + r[1] * w1 + r[2] * w2 + r[3] * w3;
        }
    }
    const float* vmain = side ? vl : vt;
    float* ob = out + 4 + (size_t)side * 139264 + ((size_t)b * 544 + tc * 8) * 128 + d;
    float xpart = 0.f;
    #pragma unroll
    for (int i = 0; i < 8; ++i) {
        float atte = 1.f / (1.f + expf(-acc[i]));
        ob[i * 128] = atte;
        xpart += vd_row(vmain, v0, v1, v2, b, tc * 8 + i)[d] * (0.5f + atte);
    }
    atomicAdd(&x4[(tc & 3) * 512 + b * 256 + side * 128 + d], xpart);
}

// K4: entire MLP in one dispatch. 16 blocks (8 per batch); two 16-block ticket
// barriers. Post-barrier phases read FRESH weights (W2/W3 first touch), so the
// fence's cache invalidation costs ~nothing (R6 lesson: only re-reads pay).
__global__ __launch_bounds__(256) void k_mlp(const float* __restrict__ x4,
                                             const float* __restrict__ W1, const float* __restrict__ b1,
                                             const float* __restrict__ W2, const float* __restrict__ b2,
                                             const float* __restrict__ W3, const float* __restrict__ b3,
                                             const float* __restrict__ Wo, const float* __restrict__ bo,
                                             float* __restrict__ f1v, float* __restrict__ f2v,
                                             float* __restrict__ out) {
    int bid = blockIdx.x, b = bid >> 3, sub = bid & 7;
    int tid = threadIdx.x, lane = tid & 63, wv = tid >> 6;
    __shared__ float buf[1024];
    __shared__ float f3s[256];

    // stage x[b] = sum of 4 slabs
    buf[tid] = (tid < 256)
        ? x4[tid + b * 256] + x4[512 + tid + b * 256] + x4[1024 + tid + b * 256] + x4[1536 + tid + b * 256]
        : 0.f;
    __syncthreads();

    // fc1: 1024 outputs per b; 8 blocks x 4 waves x 32
    for (int i = 0; i < 32; ++i) {
        int o = sub * 128 + wv * 32 + i;
        f4 w  = ((const f4*)(W1 + (size_t)o * 256))[lane];
        f4 xv = ((const f4*)buf)[lane];
        float acc = w[0]*xv[0] + w[1]*xv[1] + w[2]*xv[2] + w[3]*xv[3];
        #pragma unroll
        for (int off = 32; off > 0; off >>= 1) acc += __shfl_down(acc, off, 64);
        if (lane == 0) {
            acc += b1[o];
            f1v[b * 1024 + o] = acc > 0.f ? acc : 0.01f * acc;
        }
    }
    mlp_bar();

    for (int i = tid; i < 1024; i += 256) buf[i] = f1v[b * 1024 + i];
    __syncthreads();

    // fc2: 512 outputs per b; 8 blocks x 4 waves x 16
    for (int i = 0; i < 16; ++i) {
        int o = sub * 64 + wv * 16 + i;
        const f4* wr = (const f4*)(W2 + (size_t)o * 1024);
        const f4* xr = (const f4*)buf;
        float acc = 0.f;
        #pragma unroll
        for (int c2 = 0; c2 < 4; ++c2) {
            f4 w = wr[c2 * 64 + lane];
            f4 xv = xr[c2 * 64 + lane];
            acc += w[0]*xv[0] + w[1]*xv[1] + w[2]*xv[2] + w[3]*xv[3];
        }
        #pragma unroll
        for (int off = 32; off > 0; off >>= 1) acc += __shfl_down(acc, off, 64);
        if (lane == 0) {
            acc += b2[o];
            f2v[b * 512 + o] = acc > 0.f ? acc : 0.01f * acc;
        }
    }
    mlp_bar();
    if (sub != 0) return;

    // fc3 + pred: blocks 0 and 8 only (one per batch)
    for (int i = tid; i < 512; i += 256) buf[i] = f2v[b * 512 + i];
    __syncthreads();
    for (int i = 0; i < 64; ++i) {
        int o = wv * 64 + i;
        const f4* wr = (const f4*)(W3 + (size_t)o * 512);
        float acc = 0.f;
        #pragma unroll
        for (int c2 = 0; c2 < 2; ++c2) {
            f4 w = wr[c2 * 64 + lane];
            f4 xv = ((const f4*)buf)[c2 * 64 + lane];
            acc += w[0]*xv[0] + w[1]*xv[1] + w[2]*xv[2] + w[3]*xv[3];
        }
        #pragma unroll
        for (int off = 32; off > 0; off >>= 1) acc += __shfl_down(acc, off, 64);
        if (lane == 0) {
            acc += b3[o];
            f3s[o] = acc > 0.f ? acc : 0.01f * acc;
        }
    }
    __syncthreads();
    if (wv < 2) {
        int o = wv;
        f4 w  = ((const f4*)(Wo + o * 256))[lane];
        f4 xv = ((const f4*)f3s)[lane];
        float acc = w[0]*xv[0] + w[1]*xv[1] + w[2]*xv[2] + w[3]*xv[3];
        #pragma unroll
        for (int off = 32; off > 0; off >>= 1) acc += __shfl_down(acc, off, 64);
        if (lane == 0) out[b * 2 + o] = acc + bo[o];
    }
}

extern "C" void kernel_launch(void* const* d_in, const int* in_sizes, int n_in,
                              void* d_out, int out_size, void* d_ws, size_t ws_size,
                              hipStream_t stream) {
    (void)in_sizes; (void)n_in; (void)out_size; (void)ws_size;
    const float* v0 = (const float*)d_in[0];
    const float* v1 = (const float*)d_in[1];
    const float* v2 = (const float*)d_in[2];
    const float* vt = (const float*)d_in[3];
    const float* vl = (const float*)d_in[4];
    const float* Wt = (const float*)d_in[5];
    const float* bt = (const float*)d_in[6];
    const float* Wl = (const float*)d_in[7];
    const float* bl = (const float*)d_in[8];
    const float* Wa = (const float*)d_in[9];
    const float* ba = (const float*)d_in[10];
    const float* W1 = (const float*)d_in[11];
    const float* b1 = (const float*)d_in[12];
    const float* W2 = (const float*)d_in[13];
    const float* b2 = (const float*)d_in[14];
    const float* W3 = (const float*)d_in[15];
    const float* b3 = (const float*)d_in[16];
    const float* Wo = (const float*)d_in[17];
    const float* bo = (const float*)d_in[18];

    float* ws   = (float*)d_ws;
    float* attT = ws;                 // [2][2][128][544] = 278528
    float* S    = ws + 278528;        // [2][2][544][128] = 278528
    float* x4   = ws + 557056;        // [4][2][256]      = 2048
    float* f1v  = ws + 559104;        // [2][1024]
    float* f2v  = ws + 561152;        // [2][512]
    float* out = (float*)d_out;

    k_att<<<dim3(68, 2, 2), 128, 0, stream>>>(v0, v1, v2, vt, vl, Wt, bt, Wl, bl, attT, x4);
    k_pair<<<dim3(128, 2, 2), 256, 0, stream>>>(attT, S);
    k_atte<<<dim3(68, 2, 2), 128, 0, stream>>>(S, Wa, ba, v0, v1, v2, vt, vl, out, x4);
    k_mlp<<<MLPB, 256, 0, stream>>>(x4, W1, b1, W2, b2, W3, b3, Wo, bo, f1v, f2v, out);
}

// Round 13
// 51.179 us; speedup vs baseline: 1.8414x; 1.8414x over previous
//
#include <hip/hip_runtime.h>

typedef float f4 __attribute__((ext_vector_type(4)));

// Uniform row pointer into concatenated v_t_d / v_l_d:
// [vmain(384) | v1(64) | v2(32) | v0(64)] along tokens
__device__ __forceinline__ const float* vd_row(const float* vmain, const float* v0,
                                               const float* v1, const float* v2,
                                               int b, int t) {
    if (t < 384)      return vmain + ((size_t)b * 384 + t) * 128;
    else if (t < 448) return v1    + ((size_t)b * 64 + (t - 384)) * 128;
    else if (t < 480) return v2    + ((size_t)b * 32 + (t - 448)) * 128;
    else              return v0    + ((size_t)b * 64 + (t - 480)) * 128;
}

// Stage W[128][128] into LDS transposed: w_lds[k*129 + d] = W[d][k].
// Global reads coalesced f4; compute reads at lane=d are 2-way aliased = free.
__device__ __forceinline__ void stage_wt(const float* __restrict__ W, float* w_lds, int tid) {
    #pragma unroll 8
    for (int m = 0; m < 32; ++m) {
        int g = m * 128 + tid;          // f4 index 0..4095
        int dsrc = g >> 5;
        int k4 = (g & 31) * 4;
        f4 wv = ((const f4*)W)[g];
        w_lds[(k4 + 0) * 129 + dsrc] = wv[0];
        w_lds[(k4 + 1) * 129 + dsrc] = wv[1];
        w_lds[(k4 + 2) * 129 + dsrc] = wv[2];
        w_lds[(k4 + 3) * 129 + dsrc] = wv[3];
    }
}

// K1: att, 8 tokens/block, W self-staged transposed in LDS.
// attT[side][b][d][t] (t-contiguous for k_pair's coalesced staging).
// tc==0/side==0 blocks zero the x4 slabs.
__global__ __launch_bounds__(128) void k_att(const float* __restrict__ v0, const float* __restrict__ v1,
                                             const float* __restrict__ v2, const float* __restrict__ vt,
                                             const float* __restrict__ vl,
                                             const float* __restrict__ Wt, const float* __restrict__ bt,
                                             const float* __restrict__ Wl, const float* __restrict__ bl,
                                             float* __restrict__ attT, float* __restrict__ x4) {
    int tc = blockIdx.x, b = blockIdx.y, side = blockIdx.z;
    int d = threadIdx.x;
    __shared__ float w_lds[128 * 129];
    __shared__ float rows[8 * 128];
    if (tc == 0 && side == 0) {
        for (int i = d; i < 1024; i += 128)
            x4[(i >> 8) * 512 + b * 256 + (i & 255)] = 0.f;
    }
    const float* vmain = side ? vl : vt;
    stage_wt(side ? Wl : Wt, w_lds, d);
    #pragma unroll
    for (int i = 0; i < 8; ++i)
        rows[i * 128 + d] = vd_row(vmain, v0, v1, v2, b, tc * 8 + i)[d];
    __syncthreads();
    float bv = (side ? bl : bt)[d];
    float acc[8];
    #pragma unroll
    for (int i = 0; i < 8; ++i) acc[i] = bv;
    #pragma unroll 2
    for (int kc = 0; kc < 32; ++kc) {
        float w0 = w_lds[(kc * 4 + 0) * 129 + d];
        float w1 = w_lds[(kc * 4 + 1) * 129 + d];
        float w2 = w_lds[(kc * 4 + 2) * 129 + d];
        float w3 = w_lds[(kc * 4 + 3) * 129 + d];
        #pragma unroll
        for (int i = 0; i < 8; ++i) {
            f4 r = *(const f4*)&rows[i * 128 + kc * 4];   // LDS broadcast
            acc[i] += r[0] * w0 + r[1] * w1 + r[2] * w2 + r[3] * w3;
        }
    }
    size_t base = ((size_t)(side * 2 + b) * 128 + d) * 544 + tc * 8;
    #pragma unroll
    for (int i = 0; i < 8; ++i) attT[base + i] = acc[i];
}

// K2: S[so][b][t][d]; lrelu(x)=0.505x+0.495|x| => sum_l lrelu(c+o[l]) =
// 0.505*(544c+sum_o)+0.495*sum|c+o[l]|. Rows staged coalesced; inner loop LDS
// broadcast f4 -> 2-VALU/element floor. (Proven.)
__global__ __launch_bounds__(256, 2) void k_pair(const float* __restrict__ attT,
                                                 float* __restrict__ S) {
    const int d = blockIdx.x, b = blockIdx.y, so = blockIdx.z;
    const int tid = threadIdx.x, lane = tid & 63, wvid = tid >> 6;
    __shared__ float rows[1088];
    __shared__ float red[4];
    const float* trow_g = attT + ((size_t)(0 * 2 + b) * 128 + d) * 544;
    const float* lrow_g = attT + ((size_t)(1 * 2 + b) * 128 + d) * 544;
    for (int i = tid; i < 544; i += 256) {
        rows[i]       = trow_g[i];
        rows[544 + i] = lrow_g[i];
    }
    __syncthreads();

    const float* selfr  = rows + so * 544;
    const float* otherr = rows + (1 - so) * 544;
    float p = 0.f;
    for (int i = tid; i < 544; i += 256) p += otherr[i];
    #pragma unroll
    for (int off = 32; off > 0; off >>= 1) p += __shfl_down(p, off, 64);
    if (lane == 0) red[wvid] = p;
    __syncthreads();
    const float sum_o = red[0] + red[1] + red[2] + red[3];

    const f4* or4 = (const f4*)otherr;
    for (int t = tid; t < 544; t += 256) {
        float c = selfr[t];
        float s0 = 0.f, s1 = 0.f, s2 = 0.f, s3 = 0.f;
        #pragma unroll 4
        for (int l4 = 0; l4 < 136; ++l4) {
            f4 o = or4[l4];
            s0 += fabsf(c + o[0]);
            s1 += fabsf(c + o[1]);
            s2 += fabsf(c + o[2]);
            s3 += fabsf(c + o[3]);
        }
        float s = (s0 + s1) + (s2 + s3);
        S[((size_t)(so * 2 + b) * 544 + t) * 128 + d] =
            (0.505f * (544.f * c + sum_o) + 0.495f * s) * (1.0f / 544.f);
    }
}

// K3: atte = sigmoid(S @ Wa^T + ba), 8 tokens/block, Wa self-staged transposed;
// gated 8-token partial -> ONE atomicAdd into slab tc&3 (chain depth 17).
__global__ __launch_bounds__(128) void k_atte(const float* __restrict__ S, const float* __restrict__ Wa,
                                              const float* __restrict__ ba,
                                              const float* __restrict__ v0, const float* __restrict__ v1,
                                              const float* __restrict__ v2, const float* __restrict__ vt,
                                              const float* __restrict__ vl,
                                              float* __restrict__ out, float* __restrict__ x4) {
    int tc = blockIdx.x, b = blockIdx.y, side = blockIdx.z;
    int d = threadIdx.x;
    __shared__ float w_lds[128 * 129];
    __shared__ float srows[8 * 128];
    stage_wt(Wa, w_lds, d);
    const float* sbase = S + ((size_t)(side * 2 + b) * 544 + tc * 8) * 128;
    #pragma unroll
    for (int i = 0; i < 8; ++i) srows[i * 128 + d] = sbase[i * 128 + d];
    __syncthreads();
    float bv = ba[d];
    float acc[8];
    #pragma unroll
    for (int i = 0; i < 8; ++i) acc[i] = bv;
    #pragma unroll 2
    for (int kc = 0; kc < 32; ++kc) {
        float w0 = w_lds[(kc * 4 + 0) * 129 + d];
        float w1 = w_lds[(kc * 4 + 1) * 129 + d];
        float w2 = w_lds[(kc * 4 + 2) * 129 + d];
        float w3 = w_lds[(kc * 4 + 3) * 129 + d];
        #pragma unroll
        for (int i = 0; i < 8; ++i) {
            f4 r = *(const f4*)&srows[i * 128 + kc * 4];
            acc[i] += r[0] * w0 + r[1] * w1 + r[2] * w2 + r[3] * w3;
        }
    }
    const float* vmain = side ? vl : vt;
    float* ob = out + 4 + (size_t)side * 139264 + ((size_t)b * 544 + tc * 8) * 128 + d;
    float xpart = 0.f;
    #pragma unroll
    for (int i = 0; i < 8; ++i) {
        float atte = 1.f / (1.f + expf(-acc[i]));
        ob[i * 128] = atte;
        xpart += vd_row(vmain, v0, v1, v2, b, tc * 8 + i)[d] * (0.5f + atte);
    }
    atomicAdd(&x4[(tc & 3) * 512 + b * 256 + side * 128 + d], xpart);
}

// K4: fc1 — one wave per output (2048 waves / 512 blocks), x from the 4 slabs.
__global__ __launch_bounds__(256) void k_fc1(const float* __restrict__ x4, const float* __restrict__ W1,
                                             const float* __restrict__ b1, float* __restrict__ f1v) {
    int wave = blockIdx.x * 4 + (threadIdx.x >> 6);   // 0..2047
    int lane = threadIdx.x & 63;
    int b = wave >> 10, o = wave & 1023;
    f4 iv = ((const f4*)(x4 + 0 * 512 + b * 256))[lane]
          + ((const f4*)(x4 + 1 * 512 + b * 256))[lane]
          + ((const f4*)(x4 + 2 * 512 + b * 256))[lane]
          + ((const f4*)(x4 + 3 * 512 + b * 256))[lane];
    f4 wv = ((const f4*)(W1 + (size_t)o * 256))[lane];
    float acc = wv[0]*iv[0] + wv[1]*iv[1] + wv[2]*iv[2] + wv[3]*iv[3];
    #pragma unroll
    for (int off = 32; off > 0; off >>= 1) acc += __shfl_down(acc, off, 64);
    if (lane == 0) {
        acc += b1[o];
        f1v[wave] = acc > 0.f ? acc : 0.01f * acc;
    }
}

// K5: fc2 — one wave per output (1024 waves / 256 blocks), K=1024 -> 4 indep f4/lane.
__global__ __launch_bounds__(256) void k_fc2(const float* __restrict__ f1v, const float* __restrict__ W2,
                                             const float* __restrict__ b2, float* __restrict__ f2v) {
    int wave = blockIdx.x * 4 + (threadIdx.x >> 6);   // 0..1023
    int lane = threadIdx.x & 63;
    int b = wave >> 9, o = wave & 511;
    const f4* w2r = (const f4*)(W2 + (size_t)o * 1024);
    const f4* i2r = (const f4*)(f1v + b * 1024);
    float acc = 0.f;
    #pragma unroll
    for (int c2 = 0; c2 < 4; ++c2) {
        f4 wv = w2r[c2 * 64 + lane];
        f4 iv = i2r[c2 * 64 + lane];
        acc += wv[0]*iv[0] + wv[1]*iv[1] + wv[2]*iv[2] + wv[3]*iv[3];
    }
    #pragma unroll
    for (int off = 32; off > 0; off >>= 1) acc += __shfl_down(acc, off, 64);
    if (lane == 0) {
        acc += b2[o];
        f2v[wave] = acc > 0.f ? acc : 0.01f * acc;
    }
}

// K6: fc3 — one wave per output (512 waves / 128 blocks), K=512 -> 2 indep f4/lane.
__global__ __launch_bounds__(256) void k_fc3(const float* __restrict__ f2v, const float* __restrict__ W3,
                                             const float* __restrict__ b3, float* __restrict__ f3v) {
    int wave = blockIdx.x * 4 + (threadIdx.x >> 6);   // 0..511
    int lane = threadIdx.x & 63;
    int b = wave >> 8, o = wave & 255;
    const f4* w3r = (const f4*)(W3 + (size_t)o * 512);
    const f4* i3r = (const f4*)(f2v + b * 512);
    float acc = 0.f;
    #pragma unroll
    for (int c2 = 0; c2 < 2; ++c2) {
        f4 wv = w3r[c2 * 64 + lane];
        f4 iv = i3r[c2 * 64 + lane];
        acc += wv[0]*iv[0] + wv[1]*iv[1] + wv[2]*iv[2] + wv[3]*iv[3];
    }
    #pragma unroll
    for (int off = 32; off > 0; off >>= 1) acc += __shfl_down(acc, off, 64);
    if (lane == 0) {
        acc += b3[o];
        f3v[wave] = acc > 0.f ? acc : 0.01f * acc;
    }
}

// K7: predict — 4 waves, one per (b,o); K=256 -> 1 f4/lane.
__global__ __launch_bounds__(256) void k_pred(const float* __restrict__ f3v, const float* __restrict__ Wo,
                                              const float* __restrict__ bo, float* __restrict__ out) {
    int tid = threadIdx.x;
    int idx = tid >> 6, lane = tid & 63;
    int b = idx >> 1, o = idx & 1;
    f4 wv = ((const f4*)(Wo + o * 256))[lane];
    f4 iv = ((const f4*)(f3v + b * 256))[lane];
    float acc = wv[0]*iv[0] + wv[1]*iv[1] + wv[2]*iv[2] + wv[3]*iv[3];
    #pragma unroll
    for (int off = 32; off > 0; off >>= 1) acc += __shfl_down(acc, off, 64);
    if (lane == 0) out[b * 2 + o] = acc + bo[o];
}

extern "C" void kernel_launch(void* const* d_in, const int* in_sizes, int n_in,
                              void* d_out, int out_size, void* d_ws, size_t ws_size,
                              hipStream_t stream) {
    (void)in_sizes; (void)n_in; (void)out_size; (void)ws_size;
    const float* v0 = (const float*)d_in[0];
    const float* v1 = (const float*)d_in[1];
    const float* v2 = (const float*)d_in[2];
    const float* vt = (const float*)d_in[3];
    const float* vl = (const float*)d_in[4];
    const float* Wt = (const float*)d_in[5];
    const float* bt = (const float*)d_in[6];
    const float* Wl = (const float*)d_in[7];
    const float* bl = (const float*)d_in[8];
    const float* Wa = (const float*)d_in[9];
    const float* ba = (const float*)d_in[10];
    const float* W1 = (const float*)d_in[11];
    const float* b1 = (const float*)d_in[12];
    const float* W2 = (const float*)d_in[13];
    const float* b2 = (const float*)d_in[14];
    const float* W3 = (const float*)d_in[15];
    const float* b3 = (const float*)d_in[16];
    const float* Wo = (const float*)d_in[17];
    const float* bo = (const float*)d_in[18];

    float* ws   = (float*)d_ws;
    float* attT = ws;                 // [2][2][128][544] = 278528
    float* S    = ws + 278528;        // [2][2][544][128] = 278528
    float* x4   = ws + 557056;        // [4][2][256]      = 2048
    float* f1v  = ws + 559104;        // [2][1024]
    float* f2v  = ws + 561152;        // [2][512]
    float* f3v  = ws + 562176;        // [2][256]
    float* out = (float*)d_out;

    k_att<<<dim3(68, 2, 2), 128, 0, stream>>>(v0, v1, v2, vt, vl, Wt, bt, Wl, bl, attT, x4);
    k_pair<<<dim3(128, 2, 2), 256, 0, stream>>>(attT, S);
    k_atte<<<dim3(68, 2, 2), 128, 0, stream>>>(S, Wa, ba, v0, v1, v2, vt, vl, out, x4);
    k_fc1<<<512, 256, 0, stream>>>(x4, W1, b1, f1v);
    k_fc2<<<256, 256, 0, stream>>>(f1v, W2, b2, f2v);
    k_fc3<<<128, 256, 0, stream>>>(f2v, W3, b3, f3v);
    k_pred<<<1, 256, 0, stream>>>(f3v, Wo, bo, out);
}